// Round 6
// baseline (1579.899 us; speedup 1.0000x reference)
//
#include <hip/hip_runtime.h>

typedef unsigned short u16;
typedef __attribute__((ext_vector_type(8))) short bf16x8;
typedef __attribute__((ext_vector_type(4))) float f32x4;

__device__ __forceinline__ float bf2f(u16 u) {
  union { unsigned u; float f; } v; v.u = ((unsigned)u) << 16; return v.f;
}
__device__ __forceinline__ u16 f2bf(float f) {
  union { float f; unsigned u; } v; v.f = f;
  unsigned r = v.u + 0x7FFFu + ((v.u >> 16) & 1u);
  return (u16)(r >> 16);
}

// device-coherent (MALL) access helpers — bypass non-coherent per-XCD L2s
__device__ __forceinline__ f32x4 ld_sc_x4(const u16* p) {
  f32x4 r;
  asm volatile("global_load_dwordx4 %0, %1, off sc0 sc1"
               : "=v"(r) : "v"(p) : "memory");
  return r;
}
__device__ __forceinline__ float ld_sc_f32(const float* p) {
  float r;
  asm volatile("global_load_dword %0, %1, off sc0 sc1"
               : "=v"(r) : "v"(p) : "memory");
  return r;
}
__device__ __forceinline__ void st_sc_u16(u16* p, unsigned v) {
  asm volatile("global_store_short %0, %1, off sc0 sc1"
               :: "v"(p), "v"(v) : "memory");
}
__device__ __forceinline__ void st_sc_f32(float* p, float v) {
  asm volatile("global_store_dword %0, %1, off sc0 sc1"
               :: "v"(p), "v"(v) : "memory");
}
#define WAIT_VM0() asm volatile("s_waitcnt vmcnt(0)" ::: "memory")

__device__ __forceinline__ int ld_flag(const int* p) {
  return __hip_atomic_load(p, __ATOMIC_RELAXED, __HIP_MEMORY_SCOPE_AGENT);
}
__device__ __forceinline__ void st_flag(int* p, int v) {
  __hip_atomic_store(p, v, __ATOMIC_RELAXED, __HIP_MEMORY_SCOPE_AGENT);
}

// ---------------- scratch layout (bytes inside d_out scores region) ----------
constexpr size_t OFF_WCAT  = 0;             // bf16 [32000][1536]
constexpr size_t OFF_WSEM  = 98304000;      // bf16 [32000][1024] (later: PART)
constexpr size_t OFF_PART  = 98304000;      // f32 [128][64][768] gi1 partials
constexpr size_t OFF_H1ALL = 130000000;     // bf16 [128][16][1024]
constexpr size_t OFF_GI0   = 163840000;     // f32  [2048][3072]
constexpr size_t OFF_XOUT  = 189005824;     // bf16 [2048][1536]  (h1 | emb)
constexpr size_t OFF_H0ALL = 195297280;     // bf16 [128][16][1024]
constexpr size_t OFF_WIH0E = 199491584;     // bf16 [3072][512]
constexpr size_t OFF_WIH0S = 202637312;     // bf16 [3072][1024]  (syn slice)
constexpr size_t OFF_WHH0  = 208928768;     // bf16 [3072][1024]
constexpr size_t OFF_WIH1  = 215220224;     // bf16 [3072][1024]
constexpr size_t OFF_WHH1  = 221511680;     // bf16 [3072][1024]
constexpr size_t OFF_SYNB  = 227803136;     // bf16 [128][1024] (rows>=16 zero)
constexpr size_t OFF_SEMB  = 228065280;     // bf16 [128][1024]
constexpr size_t OFF_BASE0 = 228327424;     // f32  [128][3072]
constexpr size_t OFF_BASEO = 229900288;     // f32  [128][32000]
constexpr size_t OFF_H0IBF = 246284288;     // bf16 [16][1024]
constexpr size_t OFF_H1IBF = 246317056;     // bf16 [16][1024]
constexpr size_t OFF_FLAGS = 246349824;     // int [4096] flags (16 KB)
// real outputs
constexpr size_t OFF_HIDF  = 262144000;     // f32 [2][16][1024]
constexpr size_t OFF_LAST  = 262275072;     // f32 [16][1024]
constexpr size_t OFF_LOGIT = 262340608;     // f32 [2048][32000]

// ---------------- fp32 -> bf16 2D convert (small weights) --------------------
__global__ __launch_bounds__(256) void conv_bf16_k(
    const float* __restrict__ src, u16* __restrict__ dst,
    int rows, int cols8, int sld, int soff, int dld, int doff) {
  int t = blockIdx.x * 256 + threadIdx.x;
  if (t >= rows * cols8) return;
  int r = t / cols8, c = (t - r * cols8) * 8;
  const float* s = src + (size_t)r * sld + soff + c;
  float4 a = *(const float4*)s;
  float4 b = *(const float4*)(s + 4);
  bf16x8 o;
  o[0] = (short)f2bf(a.x); o[1] = (short)f2bf(a.y);
  o[2] = (short)f2bf(a.z); o[3] = (short)f2bf(a.w);
  o[4] = (short)f2bf(b.x); o[5] = (short)f2bf(b.y);
  o[6] = (short)f2bf(b.z); o[7] = (short)f2bf(b.w);
  *(bf16x8*)(dst + (size_t)r * dld + doff + c) = o;
}

// ---------------- merged Wout convert: one read -> WCAT + WSEM ---------------
__global__ __launch_bounds__(256) void conv_wout_k(
    const float* __restrict__ Wout, u16* __restrict__ WCAT,
    u16* __restrict__ WSEM) {
  int t = blockIdx.x * 256 + threadIdx.x;   // 32000 * 320 jobs
  int r = t / 320, c = (t - r * 320) * 8;
  const float* s = Wout + (size_t)r * 2560 + c;
  float4 a = *(const float4*)s;
  float4 b = *(const float4*)(s + 4);
  bf16x8 o;
  o[0] = (short)f2bf(a.x); o[1] = (short)f2bf(a.y);
  o[2] = (short)f2bf(a.z); o[3] = (short)f2bf(a.w);
  o[4] = (short)f2bf(b.x); o[5] = (short)f2bf(b.y);
  o[6] = (short)f2bf(b.z); o[7] = (short)f2bf(b.w);
  u16* dst;
  if (c < 1024)      dst = WCAT + (size_t)r * 1536 + c;
  else if (c < 2048) dst = WSEM + (size_t)r * 1024 + (c - 1024);
  else               dst = WCAT + (size_t)r * 1536 + 1024 + (c - 2048);
  *(bf16x8*)dst = o;
}

// ---------------- pack [16][1024] f32 -> [128][1024] bf16, rows>=16 zeroed ---
__global__ __launch_bounds__(256) void pack_pad_bf16_k(
    const float* __restrict__ src, u16* __restrict__ dst) {
  int t = blockIdx.x * 256 + threadIdx.x;
  int row = t >> 7, c = (t & 127) * 8;
  bf16x8 o = {0, 0, 0, 0, 0, 0, 0, 0};
  if (row < 16) {
    const float* s = src + row * 1024 + c;
    float4 a = *(const float4*)s;
    float4 b = *(const float4*)(s + 4);
    o[0] = (short)f2bf(a.x); o[1] = (short)f2bf(a.y);
    o[2] = (short)f2bf(a.z); o[3] = (short)f2bf(a.w);
    o[4] = (short)f2bf(b.x); o[5] = (short)f2bf(b.y);
    o[6] = (short)f2bf(b.z); o[7] = (short)f2bf(b.w);
  }
  *(bf16x8*)(dst + (size_t)row * 1024 + c) = o;
}

// ---------------- embedding gather -> bf16 into XOUT[:,1024:1536] ------------
__global__ __launch_bounds__(256) void gather_emb_k(
    const int* __restrict__ seq, const float* __restrict__ table,
    u16* __restrict__ xout) {
  int t0 = blockIdx.x * 256 + threadIdx.x;
  int tb = t0 >> 6, c = (t0 & 63) * 8;
  int tt = tb >> 4, b = tb & 15;
  int tok = seq[b * 128 + tt];
  const float* s = table + (size_t)tok * 512 + c;
  float4 a = *(const float4*)s;
  float4 bb = *(const float4*)(s + 4);
  bf16x8 o;
  o[0] = (short)f2bf(a.x);  o[1] = (short)f2bf(a.y);
  o[2] = (short)f2bf(a.z);  o[3] = (short)f2bf(a.w);
  o[4] = (short)f2bf(bb.x); o[5] = (short)f2bf(bb.y);
  o[6] = (short)f2bf(bb.z); o[7] = (short)f2bf(bb.w);
  *(bf16x8*)(xout + (size_t)tb * 1536 + 1024 + c) = o;
}

// ---------------- init bf16 h + barrier flags --------------------------------
__global__ __launch_bounds__(256) void init_h_k(
    const float* __restrict__ hidden, u16* __restrict__ h0b,
    u16* __restrict__ h1b, int* __restrict__ flags) {
  int i = blockIdx.x * 256 + threadIdx.x;   // 16384
  h0b[i] = f2bf(hidden[i]);
  h1b[i] = f2bf(hidden[16384 + i]);
  if (i < 4096) flags[i] = 0;
}

// ---------------- persistent 2-layer GRU, LDS weights, reg A-frags -----------
// 192 blocks (1/CU): 0..63 L0 (16 j, Whh0 slice); 64..127 L1-ih (Wih1 slice,
// gi1 partials one stage ahead); 128..191 L1-hh (Whh1 slice, h1 + epilogue).
// A-fragments load straight from MALL to registers (no LDS staging).
// NB: inline-asm loads REQUIRE explicit vmcnt wait + sched_barrier before any
// register-only consumer (round-5 crash: reg reuse while loads in flight).
__global__ __launch_bounds__(256, 1) void gru_persist4_k(
    const float* __restrict__ hidden, const u16* __restrict__ h0i,
    const u16* __restrict__ h1i, const float* __restrict__ gi0,
    const u16* __restrict__ Whh0, const u16* __restrict__ Wih1,
    const u16* __restrict__ Whh1, const float* __restrict__ bhh0,
    const float* __restrict__ bih1, const float* __restrict__ bhh1,
    u16* __restrict__ h0all, u16* __restrict__ h1all, u16* __restrict__ xout,
    float* __restrict__ part, float* __restrict__ hidf,
    float* __restrict__ last, int* __restrict__ flags) {
  extern __shared__ char ldsb[];
  float* Cl = (float*)(ldsb + 98304);
  const int tid = threadIdx.x, bid = blockIdx.x;
  const int wave = tid >> 6, lane = tid & 63;
  const int role = bid >> 6, lb = bid & 63, jb = lb * 16;
  int* f0 = flags;            // [64] packed
  int* fih = flags + 64;      // [64]
  int* f1 = flags + 128;      // [64]

  // ---- stage weight slice into LDS (once) ----
  const u16* Wsrc = role == 0 ? Whh0 : (role == 1 ? Wih1 : Whh1);
  for (int idx = tid; idx < 48 * 128; idx += 256) {
    int row = idx >> 7, c = idx & 127;
    int g = row >> 4, jj2 = row & 15;
    const u16* src = Wsrc + (size_t)(g * 1024 + jb + jj2) * 1024 + c * 8;
    int byte = (row * 2048 + c * 16) ^ ((row & 7) << 4);
    *(bf16x8*)(ldsb + byte) = *(const bf16x8*)src;
  }

  // ---- per-thread epilogue identity: b = tid>>4, jj = tid&15 ----
  const int eb = tid >> 4, jj = tid & 15, j = jb + jj;
  float hp = 0.f, bR = 0.f, bZ = 0.f, bN = 0.f, iR = 0.f, iZ = 0.f, iN = 0.f;
  if (role == 0) {
    hp = hidden[eb * 1024 + j];
    bR = bhh0[j]; bZ = bhh0[1024 + j]; bN = bhh0[2048 + j];
  } else if (role == 2) {
    hp = hidden[16384 + eb * 1024 + j];
    bR = bhh1[j]; bZ = bhh1[1024 + j]; bN = bhh1[2048 + j];
    iR = bih1[j]; iZ = bih1[1024 + j]; iN = bih1[2048 + j];
  }
  __syncthreads();

  const int arow = lane & 15, aq = lane >> 4;
  for (int t = 0; t < 128; ++t) {
    // ---- 1. poll producer flags (one coalesced 256B line) ----
    if (role == 0) {
      if (t > 0 && tid < 64)
        while (ld_flag(f0 + tid) < t) __builtin_amdgcn_s_sleep(1);
    } else if (role == 1) {
      if (tid < 64)
        while (ld_flag(f0 + tid) < t + 1) __builtin_amdgcn_s_sleep(1);
    } else {
      if (t > 0 && tid < 64)
        while (ld_flag(f1 + tid) < t) __builtin_amdgcn_s_sleep(1);
    }
    __syncthreads();

    // ---- 2. A-fragments: MALL -> registers directly ----
    const u16* asrc;
    if (role == 0)      asrc = t ? h0all + (size_t)(t - 1) * 16384 : h0i;
    else if (role == 1) asrc = h0all + (size_t)t * 16384;
    else                asrc = t ? h1all + (size_t)(t - 1) * 16384 : h1i;
    const u16* abase = asrc + arow * 1024 + aq * 8;
    f32x4 araw[8];
#pragma unroll
    for (int i = 0; i < 8; ++i)
      araw[i] = ld_sc_x4(abase + (wave + i * 4) * 32);
    WAIT_VM0();                              // loads landed before any use
    __builtin_amdgcn_sched_barrier(0);       // don't hoist MFMAs above wait

    // ---- 3. MFMA: 3 gate chains (ILP), B from LDS ----
    {
      f32x4 a0 = {0.f, 0.f, 0.f, 0.f}, a1 = a0, a2 = a0;
#pragma unroll
      for (int i = 0; i < 8; ++i) {
        int ks = wave + i * 4;
        bf16x8 af = *(bf16x8*)&araw[i];
        int r0 = arow, r1 = 16 + arow, r2 = 32 + arow;
        bf16x8 b0 = *(const bf16x8*)(
            ldsb + ((r0 * 2048 + ks * 64 + aq * 16) ^ ((r0 & 7) << 4)));
        bf16x8 b1 = *(const bf16x8*)(
            ldsb + ((r1 * 2048 + ks * 64 + aq * 16) ^ ((r1 & 7) << 4)));
        bf16x8 b2 = *(const bf16x8*)(
            ldsb + ((r2 * 2048 + ks * 64 + aq * 16) ^ ((r2 & 7) << 4)));
        a0 = __builtin_amdgcn_mfma_f32_16x16x32_bf16(af, b0, a0, 0, 0, 0);
        a1 = __builtin_amdgcn_mfma_f32_16x16x32_bf16(af, b1, a1, 0, 0, 0);
        a2 = __builtin_amdgcn_mfma_f32_16x16x32_bf16(af, b2, a2, 0, 0, 0);
      }
#pragma unroll
      for (int r = 0; r < 4; ++r) {
        int ci = (aq * 4 + r) * 16 + arow + aq * 8;  // conflict-break offset
        Cl[(0 * 4 + wave) * 288 + ci] = a0[r];
        Cl[(1 * 4 + wave) * 288 + ci] = a1[r];
        Cl[(2 * 4 + wave) * 288 + ci] = a2[r];
      }
    }
    if (role == 2 && tid == 0)
      while (ld_flag(fih + lb) < t + 1) __builtin_amdgcn_s_sleep(1);
    __syncthreads();

    // ---- 4. epilogue ----
    {
      int ci = eb * 16 + jj + (eb >> 2) * 8;
      float s0 = Cl[0 * 288 + ci] + Cl[1 * 288 + ci] +
                 Cl[2 * 288 + ci] + Cl[3 * 288 + ci];
      float s1 = Cl[4 * 288 + ci] + Cl[5 * 288 + ci] +
                 Cl[6 * 288 + ci] + Cl[7 * 288 + ci];
      float s2 = Cl[8 * 288 + ci] + Cl[9 * 288 + ci] +
                 Cl[10 * 288 + ci] + Cl[11 * 288 + ci];
      if (role == 1) {
        float* pp = part + ((size_t)t * 64 + lb) * 768 + eb * 16 + jj;
        st_sc_f32(pp, s0);
        st_sc_f32(pp + 256, s1);
        st_sc_f32(pp + 512, s2);
        WAIT_VM0();
      } else {
        float ir, iz, inn;
        if (role == 0) {
          const float* g = gi0 + ((size_t)t * 16 + eb) * 3072 + j;
          ir = g[0]; iz = g[1024]; inn = g[2048];
        } else {
          const float* pp = part + ((size_t)t * 64 + lb) * 768 + eb * 16 + jj;
          float p0 = ld_sc_f32(pp), p1 = ld_sc_f32(pp + 256),
                p2 = ld_sc_f32(pp + 512);
          WAIT_VM0();
          __builtin_amdgcn_sched_barrier(0);  // VALU consumers stay below
          ir = p0 + iR; iz = p1 + iZ; inn = p2 + iN;
        }
        float r = 1.f / (1.f + __expf(-(ir + s0 + bR)));
        float z = 1.f / (1.f + __expf(-(iz + s1 + bZ)));
        float n = tanhf(inn + r * (s2 + bN));
        float hnew = (1.f - z) * n + z * hp;
        hp = hnew;
        u16 hb = f2bf(hnew);
        if (role == 0) {
          st_sc_u16(h0all + ((size_t)t * 16 + eb) * 1024 + j, (unsigned)hb);
          if (t == 127) hidf[eb * 1024 + j] = hnew;
        } else {
          st_sc_u16(h1all + ((size_t)t * 16 + eb) * 1024 + j, (unsigned)hb);
          xout[((size_t)t * 16 + eb) * 1536 + j] = hb;  // plain store
          if (t == 127) {
            hidf[16384 + eb * 1024 + j] = hnew;
            last[eb * 1024 + j] = hnew;
          }
        }
        WAIT_VM0();
      }
    }
    __syncthreads();
    // ---- 5. publish flag ----
    if (tid == 0) {
      if (role == 0)      st_flag(f0 + lb, t + 1);
      else if (role == 1) st_flag(fih + lb, t + 1);
      else                st_flag(f1 + lb, t + 1);
    }
  }
}

// ---------------- bf16 MFMA GEMM: C[M,N] = A[M,K] @ B[N,K].T (+ add) ---------
// MODE 1: add[(row&15)*N + col]; 2: add[col]. SWZ: XCD-aware block remap.
template <int MODE, bool SWZ>
__global__ __launch_bounds__(256) void gemm_bt_k(
    const u16* __restrict__ A, int lda, const u16* __restrict__ Bw, int ldb,
    float* __restrict__ C, int ldc, const float* __restrict__ add,
    int N, int K) {
  __shared__ u16 Asm_[128 * 32];
  __shared__ u16 Bsm_[128 * 32];
  int bx = blockIdx.x, by = blockIdx.y;
  if (SWZ) {
    int nx = gridDim.x;
    int orig = by * nx + bx;
    int cpx = (nx * gridDim.y) >> 3;   // grid size must be divisible by 8
    int wg = (orig & 7) * cpx + (orig >> 3);
    bx = wg % nx; by = wg / nx;
  }
  const int m0 = bx * 128, n0 = by * 128;
  const int tid = threadIdx.x, wave = tid >> 6, lane = tid & 63;
  const int wm = (wave >> 1) * 64, wn = (wave & 1) * 64;
  const int lrow = lane & 15, lk = (lane >> 4) * 8;
  f32x4 acc[4][4] = {};
  for (int k0 = 0; k0 < K; k0 += 32) {
    __syncthreads();
#pragma unroll
    for (int q = 0; q < 2; ++q) {
      int c = (wave * 2 + q) * 64 + lane;
      int row = c >> 2, seg = c & 3;
      const u16* src = A + (size_t)(m0 + row) * lda + k0 + seg * 8;
      u16* dst = Asm_ + (wave * 2 + q) * 512;
      __builtin_amdgcn_global_load_lds(
          (const __attribute__((address_space(1))) void*)src,
          (__attribute__((address_space(3))) void*)dst, 16, 0, 0);
    }
#pragma unroll
    for (int q = 0; q < 2; ++q) {
      int c = (wave * 2 + q) * 64 + lane;
      int row = c >> 2, seg = c & 3;
      const u16* src = Bw + (size_t)(n0 + row) * ldb + k0 + seg * 8;
      u16* dst = Bsm_ + (wave * 2 + q) * 512;
      __builtin_amdgcn_global_load_lds(
          (const __attribute__((address_space(1))) void*)src,
          (__attribute__((address_space(3))) void*)dst, 16, 0, 0);
    }
    asm volatile("s_waitcnt vmcnt(0)" ::: "memory");
    __syncthreads();
    bf16x8 af[4], bfr[4];
#pragma unroll
    for (int i = 0; i < 4; ++i) {
      af[i]  = *(const bf16x8*)(Asm_ + (wm + i * 16 + lrow) * 32 + lk);
      bfr[i] = *(const bf16x8*)(Bsm_ + (wn + i * 16 + lrow) * 32 + lk);
    }
#pragma unroll
    for (int i = 0; i < 4; ++i)
#pragma unroll
      for (int jx = 0; jx < 4; ++jx)
        acc[i][jx] = __builtin_amdgcn_mfma_f32_16x16x32_bf16(
            af[i], bfr[jx], acc[i][jx], 0, 0, 0);
  }
  const int lr4 = (lane >> 4) * 4;
#pragma unroll
  for (int i = 0; i < 4; ++i) {
#pragma unroll
    for (int jx = 0; jx < 4; ++jx) {
      int gc = n0 + wn + jx * 16 + lrow;
#pragma unroll
      for (int r = 0; r < 4; ++r) {
        int gr = m0 + wm + i * 16 + lr4 + r;
        float v = acc[i][jx][r];
        if (MODE == 1) v += add[(gr & 15) * N + gc];
        else if (MODE == 2) v += add[gc];
        C[(size_t)gr * ldc + gc] = v;
      }
    }
  }
}

// ---------------- row-wise log_softmax, online (m,s) single read pass --------
__global__ __launch_bounds__(256) void log_softmax_k(
    const float* __restrict__ logits, float* __restrict__ scores) {
  int row = blockIdx.x;
  const float* x = logits + (size_t)row * 32000;
  float* y = scores + (size_t)row * 32000;
  __shared__ float redm[4], reds[4];
  int tid = threadIdx.x;
  float m = -3.4e38f, s = 0.f;
  for (int idx = tid * 4; idx < 32000; idx += 1024) {
    float4 v = *(const float4*)(x + idx);
    float cm = fmaxf(fmaxf(v.x, v.y), fmaxf(v.z, v.w));
    if (cm > m) { s *= __expf(m - cm); m = cm; }
    s += __expf(v.x - m) + __expf(v.y - m) + __expf(v.z - m) + __expf(v.w - m);
  }
  for (int off = 1; off < 64; off <<= 1) {
    float mo = __shfl_xor(m, off), so = __shfl_xor(s, off);
    float nm = fmaxf(m, mo);
    s = s * __expf(m - nm) + so * __expf(mo - nm);
    m = nm;
  }
  if ((tid & 63) == 0) { redm[tid >> 6] = m; reds[tid >> 6] = s; }
  __syncthreads();
  {
    float fm = fmaxf(fmaxf(redm[0], redm[1]), fmaxf(redm[2], redm[3]));
    float fs = reds[0] * __expf(redm[0] - fm) + reds[1] * __expf(redm[1] - fm) +
               reds[2] * __expf(redm[2] - fm) + reds[3] * __expf(redm[3] - fm);
    float lse = fm + logf(fs);
    for (int idx = tid * 4; idx < 32000; idx += 1024) {
      float4 v = *(const float4*)(x + idx);
      float4 o;
      o.x = v.x - lse; o.y = v.y - lse; o.z = v.z - lse; o.w = v.w - lse;
      *(float4*)(y + idx) = o;
    }
  }
}

// =============================================================================
extern "C" void kernel_launch(void* const* d_in, const int* in_sizes, int n_in,
                              void* d_out, int out_size, void* d_ws,
                              size_t ws_size, hipStream_t stream) {
  const int*   seq    = (const int*)d_in[0];
  const float* sem    = (const float*)d_in[2];
  const float* syn    = (const float*)d_in[3];
  const float* hidden = (const float*)d_in[4];
  const float* table  = (const float*)d_in[5];
  const float* Wih0   = (const float*)d_in[6];
  const float* Whh0   = (const float*)d_in[7];
  const float* bih0   = (const float*)d_in[8];
  const float* bhh0   = (const float*)d_in[9];
  const float* Wih1   = (const float*)d_in[10];
  const float* Whh1   = (const float*)d_in[11];
  const float* bih1   = (const float*)d_in[12];
  const float* bhh1   = (const float*)d_in[13];
  const float* Wout   = (const float*)d_in[14];
  const float* bout   = (const float*)d_in[15];

  char* base = (char*)d_out;
  float* scores = (float*)base;
  u16*   WCAT   = (u16*)(base + OFF_WCAT);
  u16*   WSEM   = (u16*)(base + OFF_WSEM);
  float* PART   = (float*)(base + OFF_PART);
  u16*   H1ALL  = (u16*)(base + OFF_H1ALL);
  float* GI0    = (float*)(base + OFF_GI0);
  u16*   XOUT   = (u16*)(base + OFF_XOUT);
  u16*   H0ALL  = (u16*)(base + OFF_H0ALL);
  u16*   WIH0E  = (u16*)(base + OFF_WIH0E);
  u16*   WIH0S  = (u16*)(base + OFF_WIH0S);
  u16*   WHH0B  = (u16*)(base + OFF_WHH0);
  u16*   WIH1B  = (u16*)(base + OFF_WIH1);
  u16*   WHH1B  = (u16*)(base + OFF_WHH1);
  u16*   SYNB   = (u16*)(base + OFF_SYNB);
  u16*   SEMB   = (u16*)(base + OFF_SEMB);
  float* BASE0  = (float*)(base + OFF_BASE0);
  float* BASEO  = (float*)(base + OFF_BASEO);
  u16*   H0IBF  = (u16*)(base + OFF_H0IBF);
  u16*   H1IBF  = (u16*)(base + OFF_H1IBF);
  int*   FLAGS  = (int*)(base + OFF_FLAGS);
  float* hidf   = (float*)(base + OFF_HIDF);
  float* last   = (float*)(base + OFF_LAST);
  float* logits = (float*)(base + OFF_LOGIT);

  // weight conversions to bf16 (Wout in one pass)
  conv_wout_k<<<40000, 256, 0, stream>>>(Wout, WCAT, WSEM);
  conv_bf16_k<<<768, 256, 0, stream>>>(Wih0, WIH0E, 3072, 64, 1536, 0, 512, 0);
  conv_bf16_k<<<1536, 256, 0, stream>>>(Wih0, WIH0S, 3072, 128, 1536, 512, 1024, 0);
  conv_bf16_k<<<1536, 256, 0, stream>>>(Whh0, WHH0B, 3072, 128, 1024, 0, 1024, 0);
  conv_bf16_k<<<1536, 256, 0, stream>>>(Wih1, WIH1B, 3072, 128, 1024, 0, 1024, 0);
  conv_bf16_k<<<1536, 256, 0, stream>>>(Whh1, WHH1B, 3072, 128, 1024, 0, 1024, 0);

  // embeddings + packed small operands + init
  gather_emb_k<<<512, 256, 0, stream>>>(seq, table, XOUT);
  pack_pad_bf16_k<<<64, 256, 0, stream>>>(syn, SYNB);
  pack_pad_bf16_k<<<64, 256, 0, stream>>>(sem, SEMB);
  init_h_k<<<64, 256, 0, stream>>>(hidden, H0IBF, H1IBF, FLAGS);

  // time-invariant bases via MFMA GEMM (M padded to 128; rows 16..127 junk)
  gemm_bt_k<2, false><<<dim3(1, 24), 256, 0, stream>>>(
      SYNB, 1024, WIH0S, 1024, BASE0, 3072, bih0, 3072, 1024);
  gemm_bt_k<2, false><<<dim3(1, 250), 256, 0, stream>>>(
      SEMB, 1024, WSEM, 1024, BASEO, 32000, bout, 32000, 1024);

  // gi0 for all t: embs @ Wih0e.T + base0 (grid 384 = 8*48 -> swizzle ok)
  gemm_bt_k<1, true><<<dim3(16, 24), 256, 0, stream>>>(
      XOUT + 1024, 1536, WIH0E, 512, GI0, 3072, BASE0, 3072, 512);

  // persistent recurrence: 192 blocks, LDS weights, reg A-frags, MALL dataflow
  hipFuncSetAttribute((const void*)gru_persist4_k,
                      hipFuncAttributeMaxDynamicSharedMemorySize, 114688);
  gru_persist4_k<<<192, 256, 114688, stream>>>(
      hidden, H0IBF, H1IBF, GI0, WHH0B, WIH1B, WHH1B, bhh0, bih1, bhh1,
      H0ALL, H1ALL, XOUT, PART, hidf, last, FLAGS);

  // logits = [h1 | emb] @ WCAT.T + baseo (grid 4000 = 8*500 -> XCD swizzle)
  gemm_bt_k<1, true><<<dim3(16, 250), 256, 0, stream>>>(
      XOUT, 1536, WCAT, 1536, logits, 32000, BASEO, 32000, 1536);

  // scores = log_softmax(logits) — the only writer of the scores region
  log_softmax_k<<<2048, 256, 0, stream>>>(logits, scores);
}

// Round 7
// 1412.037 us; speedup vs baseline: 1.1189x; 1.1189x over previous
//
#include <hip/hip_runtime.h>

typedef unsigned short u16;
typedef __attribute__((ext_vector_type(8))) short bf16x8;
typedef __attribute__((ext_vector_type(4))) float f32x4;
typedef __attribute__((ext_vector_type(4))) unsigned u32x4;

__device__ __forceinline__ float bf2f(u16 u) {
  union { unsigned u; float f; } v; v.u = ((unsigned)u) << 16; return v.f;
}
__device__ __forceinline__ u16 f2bf(float f) {
  union { float f; unsigned u; } v; v.f = f;
  unsigned r = v.u + 0x7FFFu + ((v.u >> 16) & 1u);
  return (u16)(r >> 16);
}

// device-coherent (MALL) access helpers — bypass non-coherent per-XCD L2s
__device__ __forceinline__ f32x4 ld_sc_x4(const u16* p) {
  f32x4 r;
  asm volatile("global_load_dwordx4 %0, %1, off sc0 sc1"
               : "=v"(r) : "v"(p) : "memory");
  return r;
}
__device__ __forceinline__ float ld_sc_f32(const float* p) {
  float r;
  asm volatile("global_load_dword %0, %1, off sc0 sc1"
               : "=v"(r) : "v"(p) : "memory");
  return r;
}
__device__ __forceinline__ void st_sc_u16(u16* p, unsigned v) {
  asm volatile("global_store_short %0, %1, off sc0 sc1"
               :: "v"(p), "v"(v) : "memory");
}
__device__ __forceinline__ void st_sc_f32(float* p, float v) {
  asm volatile("global_store_dword %0, %1, off sc0 sc1"
               :: "v"(p), "v"(v) : "memory");
}
#define WAIT_VM0() asm volatile("s_waitcnt vmcnt(0)" ::: "memory")

// ---------------- scratch layout (bytes inside d_out scores region) ----------
constexpr size_t OFF_WCAT  = 0;             // bf16 [32000][1536]
constexpr size_t OFF_WSEM  = 98304000;      // bf16 [32000][1024] (later: PART)
constexpr size_t OFF_PART  = 98304000;      // f32 [128][64][768] gi1 partials
constexpr size_t OFF_H1ALL = 130000000;     // bf16 [128][16][1024]
constexpr size_t OFF_GI0   = 163840000;     // f32  [2048][3072]
constexpr size_t OFF_XOUT  = 189005824;     // bf16 [2048][1536]  (h1 | emb)
constexpr size_t OFF_H0ALL = 195297280;     // bf16 [128][16][1024]
constexpr size_t OFF_WIH0E = 199491584;     // bf16 [3072][512]
constexpr size_t OFF_WIH0S = 202637312;     // bf16 [3072][1024]  (syn slice)
constexpr size_t OFF_WHH0  = 208928768;     // bf16 [3072][1024]
constexpr size_t OFF_WIH1  = 215220224;     // bf16 [3072][1024]
constexpr size_t OFF_WHH1  = 221511680;     // bf16 [3072][1024]
constexpr size_t OFF_SYNB  = 227803136;     // bf16 [128][1024] (rows>=16 zero)
constexpr size_t OFF_SEMB  = 228065280;     // bf16 [128][1024]
constexpr size_t OFF_BASE0 = 228327424;     // f32  [128][3072]
constexpr size_t OFF_BASEO = 229900288;     // f32  [128][32000]
constexpr size_t OFF_H0IBF = 246284288;     // bf16 [16][1024]
constexpr size_t OFF_H1IBF = 246317056;     // bf16 [16][1024]
// real outputs
constexpr size_t OFF_HIDF  = 262144000;     // f32 [2][16][1024]
constexpr size_t OFF_LAST  = 262275072;     // f32 [16][1024]
constexpr size_t OFF_LOGIT = 262340608;     // f32 [2048][32000]

// ---------------- fp32 -> bf16 2D convert (small weights) --------------------
__global__ __launch_bounds__(256) void conv_bf16_k(
    const float* __restrict__ src, u16* __restrict__ dst,
    int rows, int cols8, int sld, int soff, int dld, int doff) {
  int t = blockIdx.x * 256 + threadIdx.x;
  if (t >= rows * cols8) return;
  int r = t / cols8, c = (t - r * cols8) * 8;
  const float* s = src + (size_t)r * sld + soff + c;
  float4 a = *(const float4*)s;
  float4 b = *(const float4*)(s + 4);
  bf16x8 o;
  o[0] = (short)f2bf(a.x); o[1] = (short)f2bf(a.y);
  o[2] = (short)f2bf(a.z); o[3] = (short)f2bf(a.w);
  o[4] = (short)f2bf(b.x); o[5] = (short)f2bf(b.y);
  o[6] = (short)f2bf(b.z); o[7] = (short)f2bf(b.w);
  *(bf16x8*)(dst + (size_t)r * dld + doff + c) = o;
}

// ---------------- merged Wout convert: one read -> WCAT + WSEM ---------------
__global__ __launch_bounds__(256) void conv_wout_k(
    const float* __restrict__ Wout, u16* __restrict__ WCAT,
    u16* __restrict__ WSEM) {
  int t = blockIdx.x * 256 + threadIdx.x;   // 32000 * 320 jobs
  int r = t / 320, c = (t - r * 320) * 8;
  const float* s = Wout + (size_t)r * 2560 + c;
  float4 a = *(const float4*)s;
  float4 b = *(const float4*)(s + 4);
  bf16x8 o;
  o[0] = (short)f2bf(a.x); o[1] = (short)f2bf(a.y);
  o[2] = (short)f2bf(a.z); o[3] = (short)f2bf(a.w);
  o[4] = (short)f2bf(b.x); o[5] = (short)f2bf(b.y);
  o[6] = (short)f2bf(b.z); o[7] = (short)f2bf(b.w);
  u16* dst;
  if (c < 1024)      dst = WCAT + (size_t)r * 1536 + c;
  else if (c < 2048) dst = WSEM + (size_t)r * 1024 + (c - 1024);
  else               dst = WCAT + (size_t)r * 1536 + 1024 + (c - 2048);
  *(bf16x8*)dst = o;
}

// ---------------- pack [16][1024] f32 -> [128][1024] bf16, rows>=16 zeroed ---
__global__ __launch_bounds__(256) void pack_pad_bf16_k(
    const float* __restrict__ src, u16* __restrict__ dst) {
  int t = blockIdx.x * 256 + threadIdx.x;
  int row = t >> 7, c = (t & 127) * 8;
  bf16x8 o = {0, 0, 0, 0, 0, 0, 0, 0};
  if (row < 16) {
    const float* s = src + row * 1024 + c;
    float4 a = *(const float4*)s;
    float4 b = *(const float4*)(s + 4);
    o[0] = (short)f2bf(a.x); o[1] = (short)f2bf(a.y);
    o[2] = (short)f2bf(a.z); o[3] = (short)f2bf(a.w);
    o[4] = (short)f2bf(b.x); o[5] = (short)f2bf(b.y);
    o[6] = (short)f2bf(b.z); o[7] = (short)f2bf(b.w);
  }
  *(bf16x8*)(dst + (size_t)row * 1024 + c) = o;
}

// ---------------- embedding gather -> bf16 into XOUT[:,1024:1536] ------------
__global__ __launch_bounds__(256) void gather_emb_k(
    const int* __restrict__ seq, const float* __restrict__ table,
    u16* __restrict__ xout) {
  int t0 = blockIdx.x * 256 + threadIdx.x;
  int tb = t0 >> 6, c = (t0 & 63) * 8;
  int tt = tb >> 4, b = tb & 15;
  int tok = seq[b * 128 + tt];
  const float* s = table + (size_t)tok * 512 + c;
  float4 a = *(const float4*)s;
  float4 bb = *(const float4*)(s + 4);
  bf16x8 o;
  o[0] = (short)f2bf(a.x);  o[1] = (short)f2bf(a.y);
  o[2] = (short)f2bf(a.z);  o[3] = (short)f2bf(a.w);
  o[4] = (short)f2bf(bb.x); o[5] = (short)f2bf(bb.y);
  o[6] = (short)f2bf(bb.z); o[7] = (short)f2bf(bb.w);
  *(bf16x8*)(xout + (size_t)tb * 1536 + 1024 + c) = o;
}

// ---------------- init bf16 h --------------------------------------------
__global__ __launch_bounds__(256) void init_h_k(
    const float* __restrict__ hidden, u16* __restrict__ h0b,
    u16* __restrict__ h1b) {
  int i = blockIdx.x * 256 + threadIdx.x;   // 16384
  h0b[i] = f2bf(hidden[i]);
  h1b[i] = f2bf(hidden[16384 + i]);
}

// ---------------- sentinel fill: H0ALL/H1ALL (bf16 NaN), PART (f32 NaN) ------
// h values are in (-1,1) (z-gated tanh, h_init=0) so 0x7FC0 cannot occur;
// PART partial sums are finite so 0x7FC00000 cannot occur.
__global__ __launch_bounds__(256) void sentinel_init_k(
    u32x4* __restrict__ h0, u32x4* __restrict__ h1, u32x4* __restrict__ pt) {
  int i = blockIdx.x * 256 + threadIdx.x;   // 2,097,152 total
  u32x4 hs = {0x7FC07FC0u, 0x7FC07FC0u, 0x7FC07FC0u, 0x7FC07FC0u};
  u32x4 ps = {0x7FC00000u, 0x7FC00000u, 0x7FC00000u, 0x7FC00000u};
  if (i < 262144) h0[i] = hs;
  else if (i < 524288) h1[i - 262144] = hs;
  else pt[i - 524288] = ps;
}

// ---------------- persistent 2-layer GRU, sentinel dataflow (no flags) -------
// 192 blocks (1/CU): 0..63 L0 (16 j, Whh0); 64..127 L1-ih (Wih1, gi1 partials);
// 128..191 L1-hh (Whh1, h1 state + epilogue). Consumers poll DATA until no
// sentinel remains -> single MALL round trip per dependency.
__global__ __launch_bounds__(256, 1) void gru_persist5_k(
    const float* __restrict__ hidden, const u16* __restrict__ h0i,
    const u16* __restrict__ h1i, const float* __restrict__ gi0,
    const u16* __restrict__ Whh0, const u16* __restrict__ Wih1,
    const u16* __restrict__ Whh1, const float* __restrict__ bhh0,
    const float* __restrict__ bih1, const float* __restrict__ bhh1,
    u16* __restrict__ h0all, u16* __restrict__ h1all, u16* __restrict__ xout,
    float* __restrict__ part, float* __restrict__ hidf,
    float* __restrict__ last) {
  extern __shared__ char ldsb[];
  float* Cbuf = (float*)(ldsb + 98304);     // 2 x 3456 floats (dbuf)
  const int tid = threadIdx.x, bid = blockIdx.x;
  const int wave = tid >> 6, lane = tid & 63;
  const int role = bid >> 6, lb = bid & 63, jb = lb * 16;

  // ---- stage weight slice into LDS (once) ----
  const u16* Wsrc = role == 0 ? Whh0 : (role == 1 ? Wih1 : Whh1);
  for (int idx = tid; idx < 48 * 128; idx += 256) {
    int row = idx >> 7, c = idx & 127;
    int g = row >> 4, jj2 = row & 15;
    const u16* src = Wsrc + (size_t)(g * 1024 + jb + jj2) * 1024 + c * 8;
    int byte = (row * 2048 + c * 16) ^ ((row & 7) << 4);
    *(bf16x8*)(ldsb + byte) = *(const bf16x8*)src;
  }

  // ---- per-thread epilogue identity ----
  const int eb = tid >> 4, jj = tid & 15, j = jb + jj;
  float hp = 0.f, bR = 0.f, bZ = 0.f, bN = 0.f, iR = 0.f, iZ = 0.f, iN = 0.f;
  if (role == 0) {
    hp = hidden[eb * 1024 + j];
    bR = bhh0[j]; bZ = bhh0[1024 + j]; bN = bhh0[2048 + j];
  } else if (role == 2) {
    hp = hidden[16384 + eb * 1024 + j];
    bR = bhh1[j]; bZ = bhh1[1024 + j]; bN = bhh1[2048 + j];
    iR = bih1[j]; iZ = bih1[1024 + j]; iN = bih1[2048 + j];
  }
  __syncthreads();

  const int arow = lane & 15, aq = lane >> 4;
  for (int t = 0; t < 128; ++t) {
    float* Cl = Cbuf + (t & 1) * 3456;
    // ---- 1. A-fragments: poll-load from MALL until no sentinel ----
    const u16* asrc;
    bool poll;
    if (role == 0)      { asrc = t ? h0all + (size_t)(t - 1) * 16384 : h0i; poll = t > 0; }
    else if (role == 1) { asrc = h0all + (size_t)t * 16384; poll = true; }
    else                { asrc = t ? h1all + (size_t)(t - 1) * 16384 : h1i; poll = t > 0; }
    const u16* abase = asrc + arow * 1024 + aq * 8;
    f32x4 araw[8];
    for (;;) {
#pragma unroll
      for (int i = 0; i < 8; ++i)
        araw[i] = ld_sc_x4(abase + (wave + i * 4) * 32);
      WAIT_VM0();
      __builtin_amdgcn_sched_barrier(0);
      if (!poll) break;
      int bad = 0;
#pragma unroll
      for (int i = 0; i < 8; ++i) {
#pragma unroll
        for (int w = 0; w < 4; ++w) {
          unsigned x = __float_as_uint(araw[i][w]);
          bad |= ((x & 0xFFFFu) == 0x7FC0u) | ((x >> 16) == 0x7FC0u);
        }
      }
      if (!__any(bad)) break;
      __builtin_amdgcn_s_sleep(2);
    }

    // ---- 2. MFMA: 3 gate chains (ILP), B from LDS ----
    {
      f32x4 a0 = {0.f, 0.f, 0.f, 0.f}, a1 = a0, a2 = a0;
#pragma unroll
      for (int i = 0; i < 8; ++i) {
        int ks = wave + i * 4;
        bf16x8 af = *(bf16x8*)&araw[i];
        int r0 = arow, r1 = 16 + arow, r2 = 32 + arow;
        bf16x8 b0 = *(const bf16x8*)(
            ldsb + ((r0 * 2048 + ks * 64 + aq * 16) ^ ((r0 & 7) << 4)));
        bf16x8 b1 = *(const bf16x8*)(
            ldsb + ((r1 * 2048 + ks * 64 + aq * 16) ^ ((r1 & 7) << 4)));
        bf16x8 b2 = *(const bf16x8*)(
            ldsb + ((r2 * 2048 + ks * 64 + aq * 16) ^ ((r2 & 7) << 4)));
        a0 = __builtin_amdgcn_mfma_f32_16x16x32_bf16(af, b0, a0, 0, 0, 0);
        a1 = __builtin_amdgcn_mfma_f32_16x16x32_bf16(af, b1, a1, 0, 0, 0);
        a2 = __builtin_amdgcn_mfma_f32_16x16x32_bf16(af, b2, a2, 0, 0, 0);
      }
#pragma unroll
      for (int r = 0; r < 4; ++r) {
        int ci = (aq * 4 + r) * 16 + arow + aq * 8;  // conflict-break offset
        Cl[(0 * 4 + wave) * 288 + ci] = a0[r];
        Cl[(1 * 4 + wave) * 288 + ci] = a1[r];
        Cl[(2 * 4 + wave) * 288 + ci] = a2[r];
      }
    }
    __syncthreads();

    // ---- 3. epilogue ----
    {
      int ci = eb * 16 + jj + (eb >> 2) * 8;
      float s0 = Cl[0 * 288 + ci] + Cl[1 * 288 + ci] +
                 Cl[2 * 288 + ci] + Cl[3 * 288 + ci];
      float s1 = Cl[4 * 288 + ci] + Cl[5 * 288 + ci] +
                 Cl[6 * 288 + ci] + Cl[7 * 288 + ci];
      float s2 = Cl[8 * 288 + ci] + Cl[9 * 288 + ci] +
                 Cl[10 * 288 + ci] + Cl[11 * 288 + ci];
      if (role == 1) {
        float* pp = part + ((size_t)t * 64 + lb) * 768 + eb * 16 + jj;
        st_sc_f32(pp, s0);
        st_sc_f32(pp + 256, s1);
        st_sc_f32(pp + 512, s2);
        WAIT_VM0();   // VMEM stores read VGPRs lazily — protect data regs
      } else {
        float ir, iz, inn;
        if (role == 0) {
          const float* g = gi0 + ((size_t)t * 16 + eb) * 3072 + j;
          ir = g[0]; iz = g[1024]; inn = g[2048];
        } else {
          const float* pp = part + ((size_t)t * 64 + lb) * 768 + eb * 16 + jj;
          float p0, p1, p2;
          for (;;) {
            p0 = ld_sc_f32(pp); p1 = ld_sc_f32(pp + 256);
            p2 = ld_sc_f32(pp + 512);
            WAIT_VM0();
            __builtin_amdgcn_sched_barrier(0);
            int bad = (__float_as_uint(p0) == 0x7FC00000u) |
                      (__float_as_uint(p1) == 0x7FC00000u) |
                      (__float_as_uint(p2) == 0x7FC00000u);
            if (!__any(bad)) break;
            __builtin_amdgcn_s_sleep(2);
          }
          ir = p0 + iR; iz = p1 + iZ; inn = p2 + iN;
        }
        float r = 1.f / (1.f + __expf(-(ir + s0 + bR)));
        float z = 1.f / (1.f + __expf(-(iz + s1 + bZ)));
        float n = tanhf(inn + r * (s2 + bN));
        float hnew = (1.f - z) * n + z * hp;
        hp = hnew;
        u16 hb = f2bf(hnew);
        if (role == 0) {
          st_sc_u16(h0all + ((size_t)t * 16 + eb) * 1024 + j, (unsigned)hb);
          if (t == 127) hidf[eb * 1024 + j] = hnew;
        } else {
          st_sc_u16(h1all + ((size_t)t * 16 + eb) * 1024 + j, (unsigned)hb);
          xout[((size_t)t * 16 + eb) * 1536 + j] = hb;  // plain store
          if (t == 127) {
            hidf[16384 + eb * 1024 + j] = hnew;
            last[eb * 1024 + j] = hnew;
          }
        }
        WAIT_VM0();   // store-data register protection
      }
    }
    // no trailing sync: next stage writes the other C buffer
  }
}

// ---------------- bf16 MFMA GEMM: C[M,N] = A[M,K] @ B[N,K].T (+ add) ---------
// MODE 1: add[(row&15)*N + col]; 2: add[col]. SWZ: XCD-aware block remap.
template <int MODE, bool SWZ>
__global__ __launch_bounds__(256) void gemm_bt_k(
    const u16* __restrict__ A, int lda, const u16* __restrict__ Bw, int ldb,
    float* __restrict__ C, int ldc, const float* __restrict__ add,
    int N, int K) {
  __shared__ u16 Asm_[128 * 32];
  __shared__ u16 Bsm_[128 * 32];
  int bx = blockIdx.x, by = blockIdx.y;
  if (SWZ) {
    int nx = gridDim.x;
    int orig = by * nx + bx;
    int cpx = (nx * gridDim.y) >> 3;   // grid size must be divisible by 8
    int wg = (orig & 7) * cpx + (orig >> 3);
    bx = wg % nx; by = wg / nx;
  }
  const int m0 = bx * 128, n0 = by * 128;
  const int tid = threadIdx.x, wave = tid >> 6, lane = tid & 63;
  const int wm = (wave >> 1) * 64, wn = (wave & 1) * 64;
  const int lrow = lane & 15, lk = (lane >> 4) * 8;
  f32x4 acc[4][4] = {};
  for (int k0 = 0; k0 < K; k0 += 32) {
    __syncthreads();
#pragma unroll
    for (int q = 0; q < 2; ++q) {
      int c = (wave * 2 + q) * 64 + lane;
      int row = c >> 2, seg = c & 3;
      const u16* src = A + (size_t)(m0 + row) * lda + k0 + seg * 8;
      u16* dst = Asm_ + (wave * 2 + q) * 512;
      __builtin_amdgcn_global_load_lds(
          (const __attribute__((address_space(1))) void*)src,
          (__attribute__((address_space(3))) void*)dst, 16, 0, 0);
    }
#pragma unroll
    for (int q = 0; q < 2; ++q) {
      int c = (wave * 2 + q) * 64 + lane;
      int row = c >> 2, seg = c & 3;
      const u16* src = Bw + (size_t)(n0 + row) * ldb + k0 + seg * 8;
      u16* dst = Bsm_ + (wave * 2 + q) * 512;
      __builtin_amdgcn_global_load_lds(
          (const __attribute__((address_space(1))) void*)src,
          (__attribute__((address_space(3))) void*)dst, 16, 0, 0);
    }
    asm volatile("s_waitcnt vmcnt(0)" ::: "memory");
    __syncthreads();
    bf16x8 af[4], bfr[4];
#pragma unroll
    for (int i = 0; i < 4; ++i) {
      af[i]  = *(const bf16x8*)(Asm_ + (wm + i * 16 + lrow) * 32 + lk);
      bfr[i] = *(const bf16x8*)(Bsm_ + (wn + i * 16 + lrow) * 32 + lk);
    }
#pragma unroll
    for (int i = 0; i < 4; ++i)
#pragma unroll
      for (int jx = 0; jx < 4; ++jx)
        acc[i][jx] = __builtin_amdgcn_mfma_f32_16x16x32_bf16(
            af[i], bfr[jx], acc[i][jx], 0, 0, 0);
  }
  const int lr4 = (lane >> 4) * 4;
#pragma unroll
  for (int i = 0; i < 4; ++i) {
#pragma unroll
    for (int jx = 0; jx < 4; ++jx) {
      int gc = n0 + wn + jx * 16 + lrow;
#pragma unroll
      for (int r = 0; r < 4; ++r) {
        int gr = m0 + wm + i * 16 + lr4 + r;
        float v = acc[i][jx][r];
        if (MODE == 1) v += add[(gr & 15) * N + gc];
        else if (MODE == 2) v += add[gc];
        C[(size_t)gr * ldc + gc] = v;
      }
    }
  }
}

// ---------------- row-wise log_softmax, online (m,s) single read pass --------
__global__ __launch_bounds__(256) void log_softmax_k(
    const float* __restrict__ logits, float* __restrict__ scores) {
  int row = blockIdx.x;
  const float* x = logits + (size_t)row * 32000;
  float* y = scores + (size_t)row * 32000;
  __shared__ float redm[4], reds[4];
  int tid = threadIdx.x;
  float m = -3.4e38f, s = 0.f;
  for (int idx = tid * 4; idx < 32000; idx += 1024) {
    float4 v = *(const float4*)(x + idx);
    float cm = fmaxf(fmaxf(v.x, v.y), fmaxf(v.z, v.w));
    if (cm > m) { s *= __expf(m - cm); m = cm; }
    s += __expf(v.x - m) + __expf(v.y - m) + __expf(v.z - m) + __expf(v.w - m);
  }
  for (int off = 1; off < 64; off <<= 1) {
    float mo = __shfl_xor(m, off), so = __shfl_xor(s, off);
    float nm = fmaxf(m, mo);
    s = s * __expf(m - nm) + so * __expf(mo - nm);
    m = nm;
  }
  if ((tid & 63) == 0) { redm[tid >> 6] = m; reds[tid >> 6] = s; }
  __syncthreads();
  {
    float fm = fmaxf(fmaxf(redm[0], redm[1]), fmaxf(redm[2], redm[3]));
    float fs = reds[0] * __expf(redm[0] - fm) + reds[1] * __expf(redm[1] - fm) +
               reds[2] * __expf(redm[2] - fm) + reds[3] * __expf(redm[3] - fm);
    float lse = fm + logf(fs);
    for (int idx = tid * 4; idx < 32000; idx += 1024) {
      float4 v = *(const float4*)(x + idx);
      float4 o;
      o.x = v.x - lse; o.y = v.y - lse; o.z = v.z - lse; o.w = v.w - lse;
      *(float4*)(y + idx) = o;
    }
  }
}

// =============================================================================
extern "C" void kernel_launch(void* const* d_in, const int* in_sizes, int n_in,
                              void* d_out, int out_size, void* d_ws,
                              size_t ws_size, hipStream_t stream) {
  const int*   seq    = (const int*)d_in[0];
  const float* sem    = (const float*)d_in[2];
  const float* syn    = (const float*)d_in[3];
  const float* hidden = (const float*)d_in[4];
  const float* table  = (const float*)d_in[5];
  const float* Wih0   = (const float*)d_in[6];
  const float* Whh0   = (const float*)d_in[7];
  const float* bih0   = (const float*)d_in[8];
  const float* bhh0   = (const float*)d_in[9];
  const float* Wih1   = (const float*)d_in[10];
  const float* Whh1   = (const float*)d_in[11];
  const float* bih1   = (const float*)d_in[12];
  const float* bhh1   = (const float*)d_in[13];
  const float* Wout   = (const float*)d_in[14];
  const float* bout   = (const float*)d_in[15];

  char* base = (char*)d_out;
  float* scores = (float*)base;
  u16*   WCAT   = (u16*)(base + OFF_WCAT);
  u16*   WSEM   = (u16*)(base + OFF_WSEM);
  float* PART   = (float*)(base + OFF_PART);
  u16*   H1ALL  = (u16*)(base + OFF_H1ALL);
  float* GI0    = (float*)(base + OFF_GI0);
  u16*   XOUT   = (u16*)(base + OFF_XOUT);
  u16*   H0ALL  = (u16*)(base + OFF_H0ALL);
  u16*   WIH0E  = (u16*)(base + OFF_WIH0E);
  u16*   WIH0S  = (u16*)(base + OFF_WIH0S);
  u16*   WHH0B  = (u16*)(base + OFF_WHH0);
  u16*   WIH1B  = (u16*)(base + OFF_WIH1);
  u16*   WHH1B  = (u16*)(base + OFF_WHH1);
  u16*   SYNB   = (u16*)(base + OFF_SYNB);
  u16*   SEMB   = (u16*)(base + OFF_SEMB);
  float* BASE0  = (float*)(base + OFF_BASE0);
  float* BASEO  = (float*)(base + OFF_BASEO);
  u16*   H0IBF  = (u16*)(base + OFF_H0IBF);
  u16*   H1IBF  = (u16*)(base + OFF_H1IBF);
  float* hidf   = (float*)(base + OFF_HIDF);
  float* last   = (float*)(base + OFF_LAST);
  float* logits = (float*)(base + OFF_LOGIT);

  // weight conversions to bf16 (Wout in one pass)
  conv_wout_k<<<40000, 256, 0, stream>>>(Wout, WCAT, WSEM);
  conv_bf16_k<<<768, 256, 0, stream>>>(Wih0, WIH0E, 3072, 64, 1536, 0, 512, 0);
  conv_bf16_k<<<1536, 256, 0, stream>>>(Wih0, WIH0S, 3072, 128, 1536, 512, 1024, 0);
  conv_bf16_k<<<1536, 256, 0, stream>>>(Whh0, WHH0B, 3072, 128, 1024, 0, 1024, 0);
  conv_bf16_k<<<1536, 256, 0, stream>>>(Wih1, WIH1B, 3072, 128, 1024, 0, 1024, 0);
  conv_bf16_k<<<1536, 256, 0, stream>>>(Whh1, WHH1B, 3072, 128, 1024, 0, 1024, 0);

  // embeddings + packed small operands + init
  gather_emb_k<<<512, 256, 0, stream>>>(seq, table, XOUT);
  pack_pad_bf16_k<<<64, 256, 0, stream>>>(syn, SYNB);
  pack_pad_bf16_k<<<64, 256, 0, stream>>>(sem, SEMB);
  init_h_k<<<64, 256, 0, stream>>>(hidden, H0IBF, H1IBF);

  // time-invariant bases via MFMA GEMM (M padded to 128; rows 16..127 junk)
  gemm_bt_k<2, false><<<dim3(1, 24), 256, 0, stream>>>(
      SYNB, 1024, WIH0S, 1024, BASE0, 3072, bih0, 3072, 1024);
  gemm_bt_k<2, false><<<dim3(1, 250), 256, 0, stream>>>(
      SEMB, 1024, WSEM, 1024, BASEO, 32000, bout, 32000, 1024);

  // gi0 for all t: embs @ Wih0e.T + base0 (grid 384 = 8*48 -> swizzle ok)
  gemm_bt_k<1, true><<<dim3(16, 24), 256, 0, stream>>>(
      XOUT + 1024, 1536, WIH0E, 512, GI0, 3072, BASE0, 3072, 512);

  // sentinel fill AFTER baseo GEMM (PART/H1ALL alias the WSEM region)
  sentinel_init_k<<<8192, 256, 0, stream>>>(
      (u32x4*)H0ALL, (u32x4*)H1ALL, (u32x4*)PART);

  // persistent recurrence: sentinel dataflow, no flags
  hipFuncSetAttribute((const void*)gru_persist5_k,
                      hipFuncAttributeMaxDynamicSharedMemorySize, 125952);
  gru_persist5_k<<<192, 256, 125952, stream>>>(
      hidden, H0IBF, H1IBF, GI0, WHH0B, WIH1B, WHH1B, bhh0, bih1, bhh1,
      H0ALL, H1ALL, XOUT, PART, hidf, last);

  // logits = [h1 | emb] @ WCAT.T + baseo (grid 4000 = 8*500 -> XCD swizzle)
  gemm_bt_k<1, true><<<dim3(16, 250), 256, 0, stream>>>(
      XOUT, 1536, WCAT, 1536, logits, 32000, BASEO, 32000, 1536);

  // scores = log_softmax(logits) — the only writer of the scores region
  log_softmax_k<<<2048, 256, 0, stream>>>(logits, scores);
}

// Round 8
// 1270.412 us; speedup vs baseline: 1.2436x; 1.1115x over previous
//
#include <hip/hip_runtime.h>

typedef unsigned short u16;
typedef __attribute__((ext_vector_type(8))) short bf16x8;
typedef __attribute__((ext_vector_type(4))) float f32x4;
typedef __attribute__((ext_vector_type(4))) unsigned u32x4;

__device__ __forceinline__ float bf2f(u16 u) {
  union { unsigned u; float f; } v; v.u = ((unsigned)u) << 16; return v.f;
}
__device__ __forceinline__ u16 f2bf(float f) {
  union { float f; unsigned u; } v; v.f = f;
  unsigned r = v.u + 0x7FFFu + ((v.u >> 16) & 1u);
  return (u16)(r >> 16);
}

// device-coherent (MALL) access helpers — bypass non-coherent per-XCD L2s
__device__ __forceinline__ f32x4 ld_sc_x4(const u16* p) {
  f32x4 r;
  asm volatile("global_load_dwordx4 %0, %1, off sc0 sc1"
               : "=v"(r) : "v"(p) : "memory");
  return r;
}
__device__ __forceinline__ float ld_sc_f32(const float* p) {
  float r;
  asm volatile("global_load_dword %0, %1, off sc0 sc1"
               : "=v"(r) : "v"(p) : "memory");
  return r;
}
__device__ __forceinline__ void st_sc_u16(u16* p, unsigned v) {
  asm volatile("global_store_short %0, %1, off sc0 sc1"
               :: "v"(p), "v"(v) : "memory");
}
__device__ __forceinline__ void st_sc_f32(float* p, float v) {
  asm volatile("global_store_dword %0, %1, off sc0 sc1"
               :: "v"(p), "v"(v) : "memory");
}
#define WAIT_VM0() asm volatile("s_waitcnt vmcnt(0)" ::: "memory")

// ---------------- scratch layout (bytes inside d_out scores region) ----------
constexpr size_t OFF_WCAT  = 0;             // bf16 [32000][1536]
constexpr size_t OFF_WSEM  = 98304000;      // bf16 [32000][1024] (later: PART)
constexpr size_t OFF_PART  = 98304000;      // f32 [128][64][768] gi1 partials
constexpr size_t OFF_H1ALL = 130000000;     // bf16 [128][16][1024]
constexpr size_t OFF_GI0   = 163840000;     // f32  [2048][3072]
constexpr size_t OFF_XOUT  = 189005824;     // bf16 [2048][1536]  (h1 | emb)
constexpr size_t OFF_H0ALL = 195297280;     // bf16 [128][16][1024]
constexpr size_t OFF_WIH0E = 199491584;     // bf16 [3072][512]
constexpr size_t OFF_WIH0S = 202637312;     // bf16 [3072][1024]  (syn slice)
constexpr size_t OFF_WHH0  = 208928768;     // bf16 [3072][1024]
constexpr size_t OFF_WIH1  = 215220224;     // bf16 [3072][1024]
constexpr size_t OFF_WHH1  = 221511680;     // bf16 [3072][1024]
constexpr size_t OFF_SYNB  = 227803136;     // bf16 [128][1024] (rows>=16 zero)
constexpr size_t OFF_SEMB  = 228065280;     // bf16 [128][1024]
constexpr size_t OFF_BASE0 = 228327424;     // f32  [128][3072]
constexpr size_t OFF_BASEO = 229900288;     // f32  [128][32000]
constexpr size_t OFF_H0IBF = 246284288;     // bf16 [16][1024]
constexpr size_t OFF_H1IBF = 246317056;     // bf16 [16][1024]
// real outputs
constexpr size_t OFF_HIDF  = 262144000;     // f32 [2][16][1024]
constexpr size_t OFF_LAST  = 262275072;     // f32 [16][1024]
constexpr size_t OFF_LOGIT = 262340608;     // f32 [2048][32000]

// ---------------- fp32 -> bf16 2D convert (small weights) --------------------
__global__ __launch_bounds__(256) void conv_bf16_k(
    const float* __restrict__ src, u16* __restrict__ dst,
    int rows, int cols8, int sld, int soff, int dld, int doff) {
  int t = blockIdx.x * 256 + threadIdx.x;
  if (t >= rows * cols8) return;
  int r = t / cols8, c = (t - r * cols8) * 8;
  const float* s = src + (size_t)r * sld + soff + c;
  float4 a = *(const float4*)s;
  float4 b = *(const float4*)(s + 4);
  bf16x8 o;
  o[0] = (short)f2bf(a.x); o[1] = (short)f2bf(a.y);
  o[2] = (short)f2bf(a.z); o[3] = (short)f2bf(a.w);
  o[4] = (short)f2bf(b.x); o[5] = (short)f2bf(b.y);
  o[6] = (short)f2bf(b.z); o[7] = (short)f2bf(b.w);
  *(bf16x8*)(dst + (size_t)r * dld + doff + c) = o;
}

// ---------------- merged Wout convert: one read -> WCAT + WSEM ---------------
__global__ __launch_bounds__(256) void conv_wout_k(
    const float* __restrict__ Wout, u16* __restrict__ WCAT,
    u16* __restrict__ WSEM) {
  int t = blockIdx.x * 256 + threadIdx.x;   // 32000 * 320 jobs
  int r = t / 320, c = (t - r * 320) * 8;
  const float* s = Wout + (size_t)r * 2560 + c;
  float4 a = *(const float4*)s;
  float4 b = *(const float4*)(s + 4);
  bf16x8 o;
  o[0] = (short)f2bf(a.x); o[1] = (short)f2bf(a.y);
  o[2] = (short)f2bf(a.z); o[3] = (short)f2bf(a.w);
  o[4] = (short)f2bf(b.x); o[5] = (short)f2bf(b.y);
  o[6] = (short)f2bf(b.z); o[7] = (short)f2bf(b.w);
  u16* dst;
  if (c < 1024)      dst = WCAT + (size_t)r * 1536 + c;
  else if (c < 2048) dst = WSEM + (size_t)r * 1024 + (c - 1024);
  else               dst = WCAT + (size_t)r * 1536 + 1024 + (c - 2048);
  *(bf16x8*)dst = o;
}

// ---------------- pack [16][1024] f32 -> [128][1024] bf16, rows>=16 zeroed ---
__global__ __launch_bounds__(256) void pack_pad_bf16_k(
    const float* __restrict__ src, u16* __restrict__ dst) {
  int t = blockIdx.x * 256 + threadIdx.x;
  int row = t >> 7, c = (t & 127) * 8;
  bf16x8 o = {0, 0, 0, 0, 0, 0, 0, 0};
  if (row < 16) {
    const float* s = src + row * 1024 + c;
    float4 a = *(const float4*)s;
    float4 b = *(const float4*)(s + 4);
    o[0] = (short)f2bf(a.x); o[1] = (short)f2bf(a.y);
    o[2] = (short)f2bf(a.z); o[3] = (short)f2bf(a.w);
    o[4] = (short)f2bf(b.x); o[5] = (short)f2bf(b.y);
    o[6] = (short)f2bf(b.z); o[7] = (short)f2bf(b.w);
  }
  *(bf16x8*)(dst + (size_t)row * 1024 + c) = o;
}

// ---------------- embedding gather -> bf16 into XOUT[:,1024:1536] ------------
__global__ __launch_bounds__(256) void gather_emb_k(
    const int* __restrict__ seq, const float* __restrict__ table,
    u16* __restrict__ xout) {
  int t0 = blockIdx.x * 256 + threadIdx.x;
  int tb = t0 >> 6, c = (t0 & 63) * 8;
  int tt = tb >> 4, b = tb & 15;
  int tok = seq[b * 128 + tt];
  const float* s = table + (size_t)tok * 512 + c;
  float4 a = *(const float4*)s;
  float4 bb = *(const float4*)(s + 4);
  bf16x8 o;
  o[0] = (short)f2bf(a.x);  o[1] = (short)f2bf(a.y);
  o[2] = (short)f2bf(a.z);  o[3] = (short)f2bf(a.w);
  o[4] = (short)f2bf(bb.x); o[5] = (short)f2bf(bb.y);
  o[6] = (short)f2bf(bb.z); o[7] = (short)f2bf(bb.w);
  *(bf16x8*)(xout + (size_t)tb * 1536 + 1024 + c) = o;
}

// ---------------- init bf16 h ------------------------------------------------
__global__ __launch_bounds__(256) void init_h_k(
    const float* __restrict__ hidden, u16* __restrict__ h0b,
    u16* __restrict__ h1b) {
  int i = blockIdx.x * 256 + threadIdx.x;   // 16384
  h0b[i] = f2bf(hidden[i]);
  h1b[i] = f2bf(hidden[16384 + i]);
}

// ---------------- sentinel fill: H0ALL/H1ALL (bf16 NaN), PART (f32 NaN) ------
// h values stay in (-1,1) (z-gated tanh, h_init = 0) so 0x7FC0 cannot occur;
// PART partials are finite so 0x7FC00000 cannot occur.
__global__ __launch_bounds__(256) void sentinel_init_k(
    u32x4* __restrict__ h0, u32x4* __restrict__ h1, u32x4* __restrict__ pt) {
  int i = blockIdx.x * 256 + threadIdx.x;   // 2,097,152 total
  u32x4 hs = {0x7FC07FC0u, 0x7FC07FC0u, 0x7FC07FC0u, 0x7FC07FC0u};
  u32x4 ps = {0x7FC00000u, 0x7FC00000u, 0x7FC00000u, 0x7FC00000u};
  if (i < 262144) h0[i] = hs;
  else if (i < 524288) h1[i - 262144] = hs;
  else pt[i - 524288] = ps;
}

// ---------------- coalesced sentinel-poll stage: [16][1024] -> swizzled LDS --
__device__ __forceinline__ void stage_tile_sent(const u16* src, char* tile,
                                                int tid, bool poll) {
  f32x4 tmp[8];
  for (;;) {
#pragma unroll
    for (int q = 0; q < 8; ++q) {
      int c = q * 256 + tid;
      int row = c >> 7, kc = c & 127;
      tmp[q] = ld_sc_x4(src + (size_t)row * 1024 + kc * 8);
    }
    WAIT_VM0();
    __builtin_amdgcn_sched_barrier(0);
    if (!poll) break;
    int bad = 0;
#pragma unroll
    for (int q = 0; q < 8; ++q) {
#pragma unroll
      for (int w = 0; w < 4; ++w) {
        unsigned x = __float_as_uint(tmp[q][w]);
        bad |= ((x & 0xFFFFu) == 0x7FC0u) | ((x >> 16) == 0x7FC0u);
      }
    }
    if (!bad) break;                 // per-lane wait; wave converges naturally
    __builtin_amdgcn_s_sleep(2);
  }
#pragma unroll
  for (int q = 0; q < 8; ++q) {
    int c = q * 256 + tid;
    int row = c >> 7, kc = c & 127;
    int byte = (row * 2048 + kc * 16) ^ ((row & 7) << 4);
    *(bf16x8*)(tile + byte) = *(bf16x8*)&tmp[q];
  }
}

// ---------------- persistent 2-layer GRU: sentinel dataflow, LDS A-staging ---
// 192 blocks (1/CU): 0..63 L0 (16 j, Whh0); 64..127 L1-ih (Wih1, gi1 partials);
// 128..191 L1-hh (Whh1, h1 state + epilogue). 2 barriers/stage (C dbuf).
// LDS: [0,98304) W slice; [98304,131072) A tile; [131072,158720) C dbuf.
__global__ __launch_bounds__(256, 1) void gru_persist6_k(
    const float* __restrict__ hidden, const u16* __restrict__ h0i,
    const u16* __restrict__ h1i, const float* __restrict__ gi0,
    const u16* __restrict__ Whh0, const u16* __restrict__ Wih1,
    const u16* __restrict__ Whh1, const float* __restrict__ bhh0,
    const float* __restrict__ bih1, const float* __restrict__ bhh1,
    u16* __restrict__ h0all, u16* __restrict__ h1all, u16* __restrict__ xout,
    float* __restrict__ part, float* __restrict__ hidf,
    float* __restrict__ last) {
  extern __shared__ char ldsb[];
  char* Ab = ldsb + 98304;
  float* Cbuf = (float*)(ldsb + 131072);    // 2 x 3456 floats
  const int tid = threadIdx.x, bid = blockIdx.x;
  const int wave = tid >> 6, lane = tid & 63;
  const int role = bid >> 6, lb = bid & 63, jb = lb * 16;

  // ---- stage weight slice into LDS (once) ----
  const u16* Wsrc = role == 0 ? Whh0 : (role == 1 ? Wih1 : Whh1);
  for (int idx = tid; idx < 48 * 128; idx += 256) {
    int row = idx >> 7, c = idx & 127;
    int g = row >> 4, jj2 = row & 15;
    const u16* src = Wsrc + (size_t)(g * 1024 + jb + jj2) * 1024 + c * 8;
    int byte = (row * 2048 + c * 16) ^ ((row & 7) << 4);
    *(bf16x8*)(ldsb + byte) = *(const bf16x8*)src;
  }

  // ---- per-thread epilogue identity ----
  const int eb = tid >> 4, jj = tid & 15, j = jb + jj;
  float hp = 0.f, bR = 0.f, bZ = 0.f, bN = 0.f, iR = 0.f, iZ = 0.f, iN = 0.f;
  if (role == 0) {
    hp = hidden[eb * 1024 + j];
    bR = bhh0[j]; bZ = bhh0[1024 + j]; bN = bhh0[2048 + j];
  } else if (role == 2) {
    hp = hidden[16384 + eb * 1024 + j];
    bR = bhh1[j]; bZ = bhh1[1024 + j]; bN = bhh1[2048 + j];
    iR = bih1[j]; iZ = bih1[1024 + j]; iN = bih1[2048 + j];
  }
  __syncthreads();

  const int arow = lane & 15, aq = lane >> 4;
  for (int t = 0; t < 128; ++t) {
    float* Cl = Cbuf + (t & 1) * 3456;
    // ---- 1. stage A tile: coalesced sentinel-poll loads -> swizzled LDS ----
    const u16* asrc;
    bool poll;
    if (role == 0)      { asrc = t ? h0all + (size_t)(t - 1) * 16384 : h0i; poll = t > 0; }
    else if (role == 1) { asrc = h0all + (size_t)t * 16384; poll = true; }
    else                { asrc = t ? h1all + (size_t)(t - 1) * 16384 : h1i; poll = t > 0; }
    stage_tile_sent(asrc, Ab, tid, poll);
    __syncthreads();

    // ---- 2. MFMA: 3 gate chains (ILP), A+B from LDS ----
    {
      f32x4 a0 = {0.f, 0.f, 0.f, 0.f}, a1 = a0, a2 = a0;
#pragma unroll
      for (int i = 0; i < 8; ++i) {
        int ks = wave + i * 4;
        int abyte = (arow * 2048 + ks * 64 + aq * 16) ^ ((arow & 7) << 4);
        bf16x8 af = *(const bf16x8*)(Ab + abyte);
        int r0 = arow, r1 = 16 + arow, r2 = 32 + arow;
        bf16x8 b0 = *(const bf16x8*)(
            ldsb + ((r0 * 2048 + ks * 64 + aq * 16) ^ ((r0 & 7) << 4)));
        bf16x8 b1 = *(const bf16x8*)(
            ldsb + ((r1 * 2048 + ks * 64 + aq * 16) ^ ((r1 & 7) << 4)));
        bf16x8 b2 = *(const bf16x8*)(
            ldsb + ((r2 * 2048 + ks * 64 + aq * 16) ^ ((r2 & 7) << 4)));
        a0 = __builtin_amdgcn_mfma_f32_16x16x32_bf16(af, b0, a0, 0, 0, 0);
        a1 = __builtin_amdgcn_mfma_f32_16x16x32_bf16(af, b1, a1, 0, 0, 0);
        a2 = __builtin_amdgcn_mfma_f32_16x16x32_bf16(af, b2, a2, 0, 0, 0);
      }
#pragma unroll
      for (int r = 0; r < 4; ++r) {
        int ci = (aq * 4 + r) * 16 + arow + aq * 8;  // conflict-break offset
        Cl[(0 * 4 + wave) * 288 + ci] = a0[r];
        Cl[(1 * 4 + wave) * 288 + ci] = a1[r];
        Cl[(2 * 4 + wave) * 288 + ci] = a2[r];
      }
    }
    __syncthreads();

    // ---- 3. epilogue ----
    {
      int ci = eb * 16 + jj + (eb >> 2) * 8;
      float s0 = Cl[0 * 288 + ci] + Cl[1 * 288 + ci] +
                 Cl[2 * 288 + ci] + Cl[3 * 288 + ci];
      float s1 = Cl[4 * 288 + ci] + Cl[5 * 288 + ci] +
                 Cl[6 * 288 + ci] + Cl[7 * 288 + ci];
      float s2 = Cl[8 * 288 + ci] + Cl[9 * 288 + ci] +
                 Cl[10 * 288 + ci] + Cl[11 * 288 + ci];
      if (role == 1) {
        float* pp = part + ((size_t)t * 64 + lb) * 768 + eb * 16 + jj;
        st_sc_f32(pp, s0);
        st_sc_f32(pp + 256, s1);
        st_sc_f32(pp + 512, s2);
        WAIT_VM0();   // VMEM stores read VGPRs lazily — protect data regs
      } else {
        float ir, iz, inn;
        if (role == 0) {
          const float* g = gi0 + ((size_t)t * 16 + eb) * 3072 + j;
          ir = g[0]; iz = g[1024]; inn = g[2048];
        } else {
          const float* pp = part + ((size_t)t * 64 + lb) * 768 + eb * 16 + jj;
          float p0, p1, p2;
          for (;;) {
            p0 = ld_sc_f32(pp); p1 = ld_sc_f32(pp + 256);
            p2 = ld_sc_f32(pp + 512);
            WAIT_VM0();
            __builtin_amdgcn_sched_barrier(0);
            int bad = (__float_as_uint(p0) == 0x7FC00000u) |
                      (__float_as_uint(p1) == 0x7FC00000u) |
                      (__float_as_uint(p2) == 0x7FC00000u);
            if (!bad) break;
            __builtin_amdgcn_s_sleep(2);
          }
          ir = p0 + iR; iz = p1 + iZ; inn = p2 + iN;
        }
        float r = 1.f / (1.f + __expf(-(ir + s0 + bR)));
        float z = 1.f / (1.f + __expf(-(iz + s1 + bZ)));
        float n = tanhf(inn + r * (s2 + bN));
        float hnew = (1.f - z) * n + z * hp;
        hp = hnew;
        u16 hb = f2bf(hnew);
        if (role == 0) {
          st_sc_u16(h0all + ((size_t)t * 16 + eb) * 1024 + j, (unsigned)hb);
          if (t == 127) hidf[eb * 1024 + j] = hnew;
        } else {
          st_sc_u16(h1all + ((size_t)t * 16 + eb) * 1024 + j, (unsigned)hb);
          xout[((size_t)t * 16 + eb) * 1536 + j] = hb;  // plain store
          if (t == 127) {
            hidf[16384 + eb * 1024 + j] = hnew;
            last[eb * 1024 + j] = hnew;
          }
        }
        WAIT_VM0();   // store-data register protection
      }
    }
    // no trailing barrier: next stage writes Ab only after barrier 1, and the
    // other C buffer; all MFMA/epilogue reads are barrier-protected above.
  }
}

// ---------------- bf16 MFMA GEMM (BM=128): for M=128-padded base GEMMs -------
template <int MODE>
__global__ __launch_bounds__(256) void gemm_bt_k(
    const u16* __restrict__ A, int lda, const u16* __restrict__ Bw, int ldb,
    float* __restrict__ C, int ldc, const float* __restrict__ add,
    int N, int K) {
  __shared__ u16 Asm_[128 * 32];
  __shared__ u16 Bsm_[128 * 32];
  const int m0 = blockIdx.x * 128, n0 = blockIdx.y * 128;
  const int tid = threadIdx.x, wave = tid >> 6, lane = tid & 63;
  const int wm = (wave >> 1) * 64, wn = (wave & 1) * 64;
  const int lrow = lane & 15, lk = (lane >> 4) * 8;
  f32x4 acc[4][4] = {};
  for (int k0 = 0; k0 < K; k0 += 32) {
    __syncthreads();
#pragma unroll
    for (int q = 0; q < 2; ++q) {
      int c = (wave * 2 + q) * 64 + lane;
      int row = c >> 2, seg = c & 3;
      const u16* src = A + (size_t)(m0 + row) * lda + k0 + seg * 8;
      u16* dst = Asm_ + (wave * 2 + q) * 512;
      __builtin_amdgcn_global_load_lds(
          (const __attribute__((address_space(1))) void*)src,
          (__attribute__((address_space(3))) void*)dst, 16, 0, 0);
    }
#pragma unroll
    for (int q = 0; q < 2; ++q) {
      int c = (wave * 2 + q) * 64 + lane;
      int row = c >> 2, seg = c & 3;
      const u16* src = Bw + (size_t)(n0 + row) * ldb + k0 + seg * 8;
      u16* dst = Bsm_ + (wave * 2 + q) * 512;
      __builtin_amdgcn_global_load_lds(
          (const __attribute__((address_space(1))) void*)src,
          (__attribute__((address_space(3))) void*)dst, 16, 0, 0);
    }
    asm volatile("s_waitcnt vmcnt(0)" ::: "memory");
    __syncthreads();
    bf16x8 af[4], bfr[4];
#pragma unroll
    for (int i = 0; i < 4; ++i) {
      af[i]  = *(const bf16x8*)(Asm_ + (wm + i * 16 + lrow) * 32 + lk);
      bfr[i] = *(const bf16x8*)(Bsm_ + (wn + i * 16 + lrow) * 32 + lk);
    }
#pragma unroll
    for (int i = 0; i < 4; ++i)
#pragma unroll
      for (int jx = 0; jx < 4; ++jx)
        acc[i][jx] = __builtin_amdgcn_mfma_f32_16x16x32_bf16(
            af[i], bfr[jx], acc[i][jx], 0, 0, 0);
  }
  const int lr4 = (lane >> 4) * 4;
#pragma unroll
  for (int i = 0; i < 4; ++i) {
#pragma unroll
    for (int jx = 0; jx < 4; ++jx) {
      int gc = n0 + wn + jx * 16 + lrow;
#pragma unroll
      for (int r = 0; r < 4; ++r) {
        int gr = m0 + wm + i * 16 + lr4 + r;
        float v = acc[i][jx][r];
        if (MODE == 1) v += add[(gr & 15) * N + gc];
        else if (MODE == 2) v += add[gc];
        C[(size_t)gr * ldc + gc] = v;
      }
    }
  }
}

// ---------------- bf16 MFMA GEMM (BM=256, 512 thr, 8 waves) ------------------
// Halves B re-reads vs BM=128 (M=2048 -> 8 row-blocks instead of 16).
template <int MODE, bool SWZ>
__global__ __launch_bounds__(512) void gemm256_bt_k(
    const u16* __restrict__ A, int lda, const u16* __restrict__ Bw, int ldb,
    float* __restrict__ C, int ldc, const float* __restrict__ add,
    int N, int K) {
  __shared__ u16 Asm_[256 * 32];
  __shared__ u16 Bsm_[128 * 32];
  int bx = blockIdx.x, by = blockIdx.y;
  if (SWZ) {
    int nx = gridDim.x;
    int orig = by * nx + bx;
    int cpx = (nx * gridDim.y) >> 3;   // grid size must be divisible by 8
    int wg = (orig & 7) * cpx + (orig >> 3);
    bx = wg % nx; by = wg / nx;
  }
  const int m0 = bx * 256, n0 = by * 128;
  const int tid = threadIdx.x, wave = tid >> 6, lane = tid & 63;
  const int wm = (wave >> 1) * 64, wn = (wave & 1) * 64;
  const int lrow = lane & 15, lk = (lane >> 4) * 8;
  f32x4 acc[4][4] = {};
  for (int k0 = 0; k0 < K; k0 += 32) {
    __syncthreads();
#pragma unroll
    for (int q = 0; q < 2; ++q) {                    // A: 256x32 = 16KB
      int c = (q * 8 + wave) * 64 + lane;
      int row = c >> 2, seg = c & 3;
      const u16* src = A + (size_t)(m0 + row) * lda + k0 + seg * 8;
      u16* dst = Asm_ + (q * 8 + wave) * 512;
      __builtin_amdgcn_global_load_lds(
          (const __attribute__((address_space(1))) void*)src,
          (__attribute__((address_space(3))) void*)dst, 16, 0, 0);
    }
    {                                                // B: 128x32 = 8KB
      int c = wave * 64 + lane;
      int row = c >> 2, seg = c & 3;
      const u16* src = Bw + (size_t)(n0 + row) * ldb + k0 + seg * 8;
      u16* dst = Bsm_ + wave * 512;
      __builtin_amdgcn_global_load_lds(
          (const __attribute__((address_space(1))) void*)src,
          (__attribute__((address_space(3))) void*)dst, 16, 0, 0);
    }
    asm volatile("s_waitcnt vmcnt(0)" ::: "memory");
    __syncthreads();
    bf16x8 af[4], bfr[4];
#pragma unroll
    for (int i = 0; i < 4; ++i) {
      af[i]  = *(const bf16x8*)(Asm_ + (wm + i * 16 + lrow) * 32 + lk);
      bfr[i] = *(const bf16x8*)(Bsm_ + (wn + i * 16 + lrow) * 32 + lk);
    }
#pragma unroll
    for (int i = 0; i < 4; ++i)
#pragma unroll
      for (int jx = 0; jx < 4; ++jx)
        acc[i][jx] = __builtin_amdgcn_mfma_f32_16x16x32_bf16(
            af[i], bfr[jx], acc[i][jx], 0, 0, 0);
  }
  const int lr4 = (lane >> 4) * 4;
#pragma unroll
  for (int i = 0; i < 4; ++i) {
#pragma unroll
    for (int jx = 0; jx < 4; ++jx) {
      int gc = n0 + wn + jx * 16 + lrow;
#pragma unroll
      for (int r = 0; r < 4; ++r) {
        int gr = m0 + wm + i * 16 + lr4 + r;
        float v = acc[i][jx][r];
        if (MODE == 1) v += add[(gr & 15) * N + gc];
        else if (MODE == 2) v += add[gc];
        C[(size_t)gr * ldc + gc] = v;
      }
    }
  }
}

// ---------------- row-wise log_softmax, online (m,s) single read pass --------
__global__ __launch_bounds__(256) void log_softmax_k(
    const float* __restrict__ logits, float* __restrict__ scores) {
  int row = blockIdx.x;
  const float* x = logits + (size_t)row * 32000;
  float* y = scores + (size_t)row * 32000;
  __shared__ float redm[4], reds[4];
  int tid = threadIdx.x;
  float m = -3.4e38f, s = 0.f;
  for (int idx = tid * 4; idx < 32000; idx += 1024) {
    float4 v = *(const float4*)(x + idx);
    float cm = fmaxf(fmaxf(v.x, v.y), fmaxf(v.z, v.w));
    if (cm > m) { s *= __expf(m - cm); m = cm; }
    s += __expf(v.x - m) + __expf(v.y - m) + __expf(v.z - m) + __expf(v.w - m);
  }
  for (int off = 1; off < 64; off <<= 1) {
    float mo = __shfl_xor(m, off), so = __shfl_xor(s, off);
    float nm = fmaxf(m, mo);
    s = s * __expf(m - nm) + so * __expf(mo - nm);
    m = nm;
  }
  if ((tid & 63) == 0) { redm[tid >> 6] = m; reds[tid >> 6] = s; }
  __syncthreads();
  {
    float fm = fmaxf(fmaxf(redm[0], redm[1]), fmaxf(redm[2], redm[3]));
    float fs = reds[0] * __expf(redm[0] - fm) + reds[1] * __expf(redm[1] - fm) +
               reds[2] * __expf(redm[2] - fm) + reds[3] * __expf(redm[3] - fm);
    float lse = fm + logf(fs);
    for (int idx = tid * 4; idx < 32000; idx += 1024) {
      float4 v = *(const float4*)(x + idx);
      float4 o;
      o.x = v.x - lse; o.y = v.y - lse; o.z = v.z - lse; o.w = v.w - lse;
      *(float4*)(y + idx) = o;
    }
  }
}

// =============================================================================
extern "C" void kernel_launch(void* const* d_in, const int* in_sizes, int n_in,
                              void* d_out, int out_size, void* d_ws,
                              size_t ws_size, hipStream_t stream) {
  const int*   seq    = (const int*)d_in[0];
  const float* sem    = (const float*)d_in[2];
  const float* syn    = (const float*)d_in[3];
  const float* hidden = (const float*)d_in[4];
  const float* table  = (const float*)d_in[5];
  const float* Wih0   = (const float*)d_in[6];
  const float* Whh0   = (const float*)d_in[7];
  const float* bih0   = (const float*)d_in[8];
  const float* bhh0   = (const float*)d_in[9];
  const float* Wih1   = (const float*)d_in[10];
  const float* Whh1   = (const float*)d_in[11];
  const float* bih1   = (const float*)d_in[12];
  const float* bhh1   = (const float*)d_in[13];
  const float* Wout   = (const float*)d_in[14];
  const float* bout   = (const float*)d_in[15];

  char* base = (char*)d_out;
  float* scores = (float*)base;
  u16*   WCAT   = (u16*)(base + OFF_WCAT);
  u16*   WSEM   = (u16*)(base + OFF_WSEM);
  float* PART   = (float*)(base + OFF_PART);
  u16*   H1ALL  = (u16*)(base + OFF_H1ALL);
  float* GI0    = (float*)(base + OFF_GI0);
  u16*   XOUT   = (u16*)(base + OFF_XOUT);
  u16*   H0ALL  = (u16*)(base + OFF_H0ALL);
  u16*   WIH0E  = (u16*)(base + OFF_WIH0E);
  u16*   WIH0S  = (u16*)(base + OFF_WIH0S);
  u16*   WHH0B  = (u16*)(base + OFF_WHH0);
  u16*   WIH1B  = (u16*)(base + OFF_WIH1);
  u16*   WHH1B  = (u16*)(base + OFF_WHH1);
  u16*   SYNB   = (u16*)(base + OFF_SYNB);
  u16*   SEMB   = (u16*)(base + OFF_SEMB);
  float* BASE0  = (float*)(base + OFF_BASE0);
  float* BASEO  = (float*)(base + OFF_BASEO);
  u16*   H0IBF  = (u16*)(base + OFF_H0IBF);
  u16*   H1IBF  = (u16*)(base + OFF_H1IBF);
  float* hidf   = (float*)(base + OFF_HIDF);
  float* last   = (float*)(base + OFF_LAST);
  float* logits = (float*)(base + OFF_LOGIT);

  // weight conversions to bf16 (Wout in one pass)
  conv_wout_k<<<40000, 256, 0, stream>>>(Wout, WCAT, WSEM);
  conv_bf16_k<<<768, 256, 0, stream>>>(Wih0, WIH0E, 3072, 64, 1536, 0, 512, 0);
  conv_bf16_k<<<1536, 256, 0, stream>>>(Wih0, WIH0S, 3072, 128, 1536, 512, 1024, 0);
  conv_bf16_k<<<1536, 256, 0, stream>>>(Whh0, WHH0B, 3072, 128, 1024, 0, 1024, 0);
  conv_bf16_k<<<1536, 256, 0, stream>>>(Wih1, WIH1B, 3072, 128, 1024, 0, 1024, 0);
  conv_bf16_k<<<1536, 256, 0, stream>>>(Whh1, WHH1B, 3072, 128, 1024, 0, 1024, 0);

  // embeddings + packed small operands + init
  gather_emb_k<<<512, 256, 0, stream>>>(seq, table, XOUT);
  pack_pad_bf16_k<<<64, 256, 0, stream>>>(syn, SYNB);
  pack_pad_bf16_k<<<64, 256, 0, stream>>>(sem, SEMB);
  init_h_k<<<64, 256, 0, stream>>>(hidden, H0IBF, H1IBF);

  // time-invariant bases via MFMA GEMM (M padded to 128; rows 16..127 junk)
  gemm_bt_k<2><<<dim3(1, 24), 256, 0, stream>>>(
      SYNB, 1024, WIH0S, 1024, BASE0, 3072, bih0, 3072, 1024);
  gemm_bt_k<2><<<dim3(1, 250), 256, 0, stream>>>(
      SEMB, 1024, WSEM, 1024, BASEO, 32000, bout, 32000, 1024);

  // gi0 for all t: embs @ Wih0e.T + base0 (BM=256 kernel, grid 192 = 8*24)
  gemm256_bt_k<1, true><<<dim3(8, 24), 512, 0, stream>>>(
      XOUT + 1024, 1536, WIH0E, 512, GI0, 3072, BASE0, 3072, 512);

  // sentinel fill AFTER baseo GEMM (PART/H1ALL alias the WSEM region)
  sentinel_init_k<<<8192, 256, 0, stream>>>(
      (u32x4*)H0ALL, (u32x4*)H1ALL, (u32x4*)PART);

  // persistent recurrence: sentinel dataflow + coalesced LDS staging
  hipFuncSetAttribute((const void*)gru_persist6_k,
                      hipFuncAttributeMaxDynamicSharedMemorySize, 158720);
  gru_persist6_k<<<192, 256, 158720, stream>>>(
      hidden, H0IBF, H1IBF, GI0, WHH0B, WIH1B, WHH1B, bhh0, bih1, bhh1,
      H0ALL, H1ALL, XOUT, PART, hidf, last);

  // logits = [h1 | emb] @ WCAT.T + baseo (BM=256, grid 2000 = 8*250, swizzle)
  gemm256_bt_k<1, true><<<dim3(8, 250), 512, 0, stream>>>(
      XOUT, 1536, WCAT, 1536, logits, 32000, BASEO, 32000, 1536);

  // scores = log_softmax(logits) — the only writer of the scores region
  log_softmax_k<<<2048, 256, 0, stream>>>(logits, scores);
}